// Round 1
// baseline (2479.464 us; speedup 1.0000x reference)
//
#include <hip/hip_runtime.h>
#include <hip/hip_bf16.h>

// ---------------------------------------------------------------------------
// CapsuleNet forward: conv1 -> primaryCaps conv -> squash -> u_hat (bf16) ->
// 3x dynamic routing -> v_j [256,10,16] fp32.
//
// Workspace layout (bytes):
//   h      @ 0          : 256*256*400 f32 = 104,857,600
//   caps   @ 104857600  : 256*1152*8 f32  =   9,437,184   (squashed in-place)
//   u_hat  @ 0 (reuse h): 256*1152*160 bf16 = 94,371,840
//   b_buf  @ 114294784  : 256*10*1152 f32 =  11,796,480   (layout [b][j][i])
//   c_buf  @ 126091264  : 256*10*1152 f32 =  11,796,480
//   v_buf  @ 137887744  : 256*160 f32     =     163,840
// total ~138 MB.
// ---------------------------------------------------------------------------

__device__ inline float bf_lo(unsigned u){ return __uint_as_float(u << 16); }
__device__ inline float bf_hi(unsigned u){ return __uint_as_float(u & 0xffff0000u); }

// conv1: x[256,1,28,28] * w[256,1,9,9] -> h[256,256,20,20]
__global__ __launch_bounds__(320) void conv1_kernel(const float* __restrict__ x,
    const float* __restrict__ w, const float* __restrict__ bias,
    float* __restrict__ h){
  __shared__ float img[784];
  __shared__ float ws[16 * 81];
  int b = blockIdx.x;
  int og = blockIdx.y;
  int t = threadIdx.x;
  const float* xb = x + (size_t)b * 784;
  for (int idx = t; idx < 784; idx += 320) img[idx] = xb[idx];
  for (int idx = t; idx < 1296; idx += 320){
    ws[idx] = w[(size_t)og * 16 * 81 + idx];
  }
  __syncthreads();
  int o_l = t / 20;        // 0..15
  int y   = t - o_l * 20;  // 0..19
  float acc[20];
  #pragma unroll
  for (int i = 0; i < 20; i++) acc[i] = 0.f;
  #pragma unroll
  for (int r = 0; r < 9; r++){
    float row[28];
    const float4* rp = (const float4*)&img[(y + r) * 28];
    #pragma unroll
    for (int q = 0; q < 7; q++){
      float4 v4 = rp[q];
      row[4*q+0]=v4.x; row[4*q+1]=v4.y; row[4*q+2]=v4.z; row[4*q+3]=v4.w;
    }
    #pragma unroll
    for (int s = 0; s < 9; s++){
      float wv = ws[o_l * 81 + r * 9 + s];
      #pragma unroll
      for (int xx = 0; xx < 20; xx++)
        acc[xx] = fmaf(wv, row[xx + s], acc[xx]);
    }
  }
  int o = og * 16 + o_l;
  float bv = bias[o];
  float* hp = h + ((size_t)b * 256 + o) * 400 + y * 20;
  #pragma unroll
  for (int xx = 0; xx < 20; xx++) hp[xx] = acc[xx] + bv;
}

// conv2 (primaryCaps): h[256,256,20,20] * w[256,256,9,9] stride2 -> caps[256,9216]
// block: 192 thr = 4 ocol x (8b x 6y); tile 16 o x 8 b; thread tile 4o x 6x.
__global__ __launch_bounds__(192) void conv2_kernel(const float* __restrict__ h,
    const float* __restrict__ w, const float* __restrict__ bias,
    float* __restrict__ caps){
  __shared__ float hs[3200];       // 8 b x 400
  __shared__ float wsT[1296];      // [k=81][o=16] transposed for float4 reads
  int o0 = blockIdx.x * 16;
  int b0 = blockIdx.y * 8;
  int t = threadIdx.x;
  int ocol  = t & 3;
  int rowid = t >> 2;       // 0..47
  int b_l = rowid / 6;      // 0..7
  int y   = rowid - b_l * 6;
  float acc[4][6];
  #pragma unroll
  for (int a = 0; a < 4; a++)
    #pragma unroll
    for (int xx = 0; xx < 6; xx++) acc[a][xx] = 0.f;

  for (int c = 0; c < 256; c++){
    __syncthreads();
    for (int idx = t; idx < 3200; idx += 192){
      int bb = idx / 400, p = idx - bb * 400;
      hs[idx] = h[((size_t)(b0 + bb) * 256 + c) * 400 + p];
    }
    for (int idx = t; idx < 1296; idx += 192){
      int o_l = idx / 81, k = idx - o_l * 81;
      wsT[k * 16 + o_l] = w[((size_t)(o0 + o_l) * 256 + c) * 81 + k];
    }
    __syncthreads();
    const float* hrow_base = &hs[b_l * 400];
    #pragma unroll
    for (int r = 0; r < 9; r++){
      float row[20];
      const float4* rp = (const float4*)&hrow_base[(2 * y + r) * 20];
      #pragma unroll
      for (int q = 0; q < 5; q++){
        float4 v4 = rp[q];
        row[4*q+0]=v4.x; row[4*q+1]=v4.y; row[4*q+2]=v4.z; row[4*q+3]=v4.w;
      }
      #pragma unroll
      for (int s = 0; s < 9; s++){
        float4 w4 = *(const float4*)&wsT[(r * 9 + s) * 16 + ocol * 4];
        #pragma unroll
        for (int xx = 0; xx < 6; xx++){
          float hv = row[2 * xx + s];
          acc[0][xx] = fmaf(w4.x, hv, acc[0][xx]);
          acc[1][xx] = fmaf(w4.y, hv, acc[1][xx]);
          acc[2][xx] = fmaf(w4.z, hv, acc[2][xx]);
          acc[3][xx] = fmaf(w4.w, hv, acc[3][xx]);
        }
      }
    }
  }
  #pragma unroll
  for (int oi = 0; oi < 4; oi++){
    int o = o0 + ocol * 4 + oi;
    float bv = bias[o];
    float* cpo = caps + (size_t)(b0 + b_l) * 9216 + (size_t)o * 36 + y * 6;
    #pragma unroll
    for (int xx = 0; xx < 6; xx++) cpo[xx] = acc[oi][xx] + bv;
  }
}

// in-place squash over last dim of caps [256*1152, 8]
__global__ __launch_bounds__(256) void squash_kernel(float* __restrict__ caps){
  size_t cid = (size_t)blockIdx.x * 256 + threadIdx.x;   // exactly 294912
  float4* p = (float4*)(caps + cid * 8);
  float4 a = p[0], b4 = p[1];
  float msq = a.x*a.x + a.y*a.y + a.z*a.z + a.w*a.w
            + b4.x*b4.x + b4.y*b4.y + b4.z*b4.z + b4.w*b4.w;
  float scale = sqrtf(msq) / (1.f + msq);   // == msq/(1+msq) / sqrt(msq)
  a.x *= scale; a.y *= scale; a.z *= scale; a.w *= scale;
  b4.x *= scale; b4.y *= scale; b4.z *= scale; b4.w *= scale;
  p[0] = a; p[1] = b4;
}

// u_hat[b,i,jd] = sum_k W[i,jd,k]*caps[b,i,k]  -> bf16, layout [b][i][160]
// block 256 (4 waves); wave handles one i; lane l covers jd = 64m+l, m=0..2
__global__ __launch_bounds__(256) void uhat_kernel(const float* __restrict__ caps,
    const float* __restrict__ Wt, __hip_bfloat16* __restrict__ uh){
  __shared__ float cl[4096];   // [16 b][32 i][8 k]
  int i0 = blockIdx.x * 32;
  int b0 = blockIdx.y * 16;
  int t = threadIdx.x;
  for (int idx = t; idx < 4096; idx += 256){
    int b_l = idx >> 8;
    int rest = idx & 255;
    cl[idx] = caps[((size_t)(b0 + b_l) * 1152 + i0 + (rest >> 3)) * 8 + (rest & 7)];
  }
  __syncthreads();
  int wid = t >> 6, l = t & 63;
  for (int ii = 0; ii < 8; ii++){
    int i = i0 + ii * 4 + wid;
    float wreg[3][8];
    #pragma unroll
    for (int m = 0; m < 3; m++){
      int jd = m * 64 + l;
      if (jd < 160){
        const float4* wp = (const float4*)&Wt[((size_t)i * 160 + jd) * 8];
        float4 p0 = wp[0], p1 = wp[1];
        wreg[m][0]=p0.x; wreg[m][1]=p0.y; wreg[m][2]=p0.z; wreg[m][3]=p0.w;
        wreg[m][4]=p1.x; wreg[m][5]=p1.y; wreg[m][6]=p1.z; wreg[m][7]=p1.w;
      }
    }
    for (int b_l = 0; b_l < 16; b_l++){
      const float4* cp4 = (const float4*)&cl[(b_l * 32 + ii * 4 + wid) * 8];
      float4 ca = cp4[0], cb = cp4[1];
      float ck[8] = {ca.x, ca.y, ca.z, ca.w, cb.x, cb.y, cb.z, cb.w};
      size_t ubase = ((size_t)(b0 + b_l) * 1152 + i) * 160;
      #pragma unroll
      for (int m = 0; m < 3; m++){
        int jd = m * 64 + l;
        if (jd < 160){
          float uv = 0.f;
          #pragma unroll
          for (int k = 0; k < 8; k++) uv = fmaf(wreg[m][k], ck[k], uv);
          uh[ubase + jd] = __float2bfloat16(uv);
        }
      }
    }
  }
}

// route A: b_ij (+)= u.v ; c = softmax_j(b).  thread-per-capsule-i.
// b_buf/c_buf layout [b][j(10)][i(1152)] for coalesced access.
__global__ __launch_bounds__(128) void routeA_kernel(const __hip_bfloat16* __restrict__ u,
    const float* __restrict__ v, float* __restrict__ bbuf, float* __restrict__ cbuf,
    int first){
  __shared__ float vs[160];
  int b = blockIdx.x;
  int ig = blockIdx.y;
  int t = threadIdx.x;
  for (int idx = t; idx < 160; idx += 128) vs[idx] = v[b * 160 + idx];
  __syncthreads();
  int i = ig * 128 + t;
  const __hip_bfloat16* up = u + ((size_t)b * 1152 + i) * 160;
  float dots[10];
  #pragma unroll
  for (int j = 0; j < 10; j++){
    const uint4* q = (const uint4*)(up + j * 16);
    uint4 a = q[0], b2 = q[1];
    unsigned wv[8] = {a.x, a.y, a.z, a.w, b2.x, b2.y, b2.z, b2.w};
    const float* vj = &vs[j * 16];
    float d0 = 0.f;
    #pragma unroll
    for (int wq = 0; wq < 8; wq++){
      d0 = fmaf(bf_lo(wv[wq]), vj[2*wq],   d0);
      d0 = fmaf(bf_hi(wv[wq]), vj[2*wq+1], d0);
    }
    dots[j] = d0;
  }
  float* bp = bbuf + (size_t)b * 11520 + i;
  if (!first){
    #pragma unroll
    for (int j = 0; j < 10; j++) dots[j] += bp[j * 1152];
  }
  #pragma unroll
  for (int j = 0; j < 10; j++) bp[j * 1152] = dots[j];
  float mx = dots[0];
  #pragma unroll
  for (int j = 1; j < 10; j++) mx = fmaxf(mx, dots[j]);
  float e[10]; float se = 0.f;
  #pragma unroll
  for (int j = 0; j < 10; j++){ e[j] = __expf(dots[j] - mx); se += e[j]; }
  float inv = 1.f / se;
  float* cp = cbuf + (size_t)b * 11520 + i;
  #pragma unroll
  for (int j = 0; j < 10; j++) cp[j * 1152] = e[j] * inv;
}

// route B: s[jd] = sum_i c[i,j]*u[i,jd] (+bias) ; v = squash_d(s)
// block 320: lane owns (ipar, jd); mode 0 => uniform c = 0.1
__global__ __launch_bounds__(320) void routeB_kernel(const __hip_bfloat16* __restrict__ u,
    const float* __restrict__ cbuf, const float* __restrict__ dcb,
    float* __restrict__ vout, int mode){
  __shared__ float sp[2][160];
  int b = blockIdx.x;
  int t = threadIdx.x;
  int ipar = t / 160;
  int jd = t - ipar * 160;
  int j = jd >> 4;
  const __hip_bfloat16* up = u + (size_t)b * 184320 + jd;
  const float* cp = cbuf + (size_t)b * 11520 + (size_t)j * 1152;
  float s = 0.f;
  if (mode){
    #pragma unroll 8
    for (int i = ipar; i < 1152; i += 2){
      float uv = __bfloat162float(up[(size_t)i * 160]);
      s = fmaf(uv, cp[i], s);
    }
  } else {
    #pragma unroll 8
    for (int i = ipar; i < 1152; i += 2){
      float uv = __bfloat162float(up[(size_t)i * 160]);
      s = fmaf(uv, 0.1f, s);
    }
  }
  sp[ipar][jd] = s;
  __syncthreads();
  if (t < 160){
    float sv = sp[0][t] + sp[1][t] + dcb[t];
    float msq = sv * sv;
    #pragma unroll
    for (int off = 1; off < 16; off <<= 1) msq += __shfl_xor(msq, off);
    float scale = sqrtf(msq) / (1.f + msq);
    vout[b * 160 + t] = sv * scale;
  }
}

extern "C" void kernel_launch(void* const* d_in, const int* in_sizes, int n_in,
                              void* d_out, int out_size, void* d_ws, size_t ws_size,
                              hipStream_t stream){
  (void)in_sizes; (void)n_in; (void)out_size; (void)ws_size;
  const float* x   = (const float*)d_in[0];
  const float* w1  = (const float*)d_in[1];
  const float* b1  = (const float*)d_in[2];
  const float* w2  = (const float*)d_in[3];
  const float* b2  = (const float*)d_in[4];
  const float* W   = (const float*)d_in[5];
  const float* dcb = (const float*)d_in[6];
  float* out = (float*)d_out;

  char* ws = (char*)d_ws;
  float* h    = (float*)(ws);
  float* caps = (float*)(ws + 104857600);
  __hip_bfloat16* uh = (__hip_bfloat16*)(ws);   // reuses h region (h dead)
  float* bbuf = (float*)(ws + 114294784);
  float* cbuf = (float*)(ws + 126091264);
  float* vbuf = (float*)(ws + 137887744);

  conv1_kernel<<<dim3(256, 16), 320, 0, stream>>>(x, w1, b1, h);
  conv2_kernel<<<dim3(16, 32), 192, 0, stream>>>(h, w2, b2, caps);
  squash_kernel<<<1152, 256, 0, stream>>>(caps);
  uhat_kernel<<<dim3(36, 16), 256, 0, stream>>>(caps, W, uh);
  // routing iteration 0: c uniform
  routeB_kernel<<<256, 320, 0, stream>>>(uh, cbuf, dcb, vbuf, 0);
  // iteration 1
  routeA_kernel<<<dim3(256, 9), 128, 0, stream>>>(uh, vbuf, bbuf, cbuf, 1);
  routeB_kernel<<<256, 320, 0, stream>>>(uh, cbuf, dcb, vbuf, 1);
  // iteration 2 (final -> d_out)
  routeA_kernel<<<dim3(256, 9), 128, 0, stream>>>(uh, vbuf, bbuf, cbuf, 0);
  routeB_kernel<<<256, 320, 0, stream>>>(uh, cbuf, dcb, out, 1);
}

// Round 2
// 840.236 us; speedup vs baseline: 2.9509x; 2.9509x over previous
//
#include <hip/hip_runtime.h>
#include <hip/hip_bf16.h>

// ---------------------------------------------------------------------------
// CapsuleNet forward. Round 2: conv2 -> bf16 MFMA implicit GEMM.
//
// Workspace layout (bytes), total ~127.6 MB:
//   region A @ 0 .. 94,371,840  : overlay
//     h_bf  @ 0          : 256*256*400 bf16 = 52,428,800   (conv phase)
//     Abf   @ 52,428,800 : 256*20736 bf16  = 10,616,832    (conv phase)
//     u_hat @ 0          : 256*1152*160 bf16 = 94,371,840  (routing phase)
//   caps @ 94,371,840  : 256*1152*8 f32 = 9,437,184
//   bbuf @ 103,809,024 : 256*10*1152 f32 = 11,796,480
//   cbuf @ 115,605,504 : 256*10*1152 f32 = 11,796,480
//   vbuf @ 127,401,984 : 256*160 f32 = 163,840
// ---------------------------------------------------------------------------

typedef __attribute__((ext_vector_type(8))) short short8;
typedef __attribute__((ext_vector_type(4))) float float4v;

__device__ inline float bf_lo(unsigned u){ return __uint_as_float(u << 16); }
__device__ inline float bf_hi(unsigned u){ return __uint_as_float(u & 0xffff0000u); }

// conv1: x[256,1,28,28] * w[256,1,9,9] -> h_bf[256,256,400] (bf16)
__global__ __launch_bounds__(320) void conv1_kernel(const float* __restrict__ x,
    const float* __restrict__ w, const float* __restrict__ bias,
    __hip_bfloat16* __restrict__ h){
  __shared__ float img[784];
  __shared__ float ws[16 * 81];
  int b = blockIdx.x;
  int og = blockIdx.y;
  int t = threadIdx.x;
  const float* xb = x + (size_t)b * 784;
  for (int idx = t; idx < 784; idx += 320) img[idx] = xb[idx];
  for (int idx = t; idx < 1296; idx += 320) ws[idx] = w[(size_t)og * 1296 + idx];
  __syncthreads();
  int o_l = t / 20;        // 0..15
  int y   = t - o_l * 20;  // 0..19
  float acc[20];
  #pragma unroll
  for (int i = 0; i < 20; i++) acc[i] = 0.f;
  #pragma unroll
  for (int r = 0; r < 9; r++){
    float row[28];
    const float4* rp = (const float4*)&img[(y + r) * 28];
    #pragma unroll
    for (int q = 0; q < 7; q++){
      float4 v4 = rp[q];
      row[4*q+0]=v4.x; row[4*q+1]=v4.y; row[4*q+2]=v4.z; row[4*q+3]=v4.w;
    }
    #pragma unroll
    for (int s = 0; s < 9; s++){
      float wv = ws[o_l * 81 + r * 9 + s];
      #pragma unroll
      for (int xx = 0; xx < 20; xx++)
        acc[xx] = fmaf(wv, row[xx + s], acc[xx]);
    }
  }
  int o = og * 16 + o_l;
  float bv = bias[o];
  __hip_bfloat16* hp = h + ((size_t)b * 256 + o) * 400 + y * 20;
  #pragma unroll
  for (int xx = 0; xx < 20; xx++) hp[xx] = __float2bfloat16(acc[xx] + bv);
}

// repack conv2 weights: Abf[o][k], k = (r*9+s)*256 + c  (bf16)
__global__ __launch_bounds__(256) void arepack_kernel(const float* __restrict__ w2,
    __hip_bfloat16* __restrict__ Abf){
  __shared__ float wbuf[64 * 81];   // 20.7 KB
  int o = blockIdx.x;
  int t = threadIdx.x;
  for (int cc0 = 0; cc0 < 256; cc0 += 64){
    __syncthreads();
    for (int idx = t; idx < 5184; idx += 256)
      wbuf[idx] = w2[(size_t)o * 20736 + (size_t)cc0 * 81 + idx];
    __syncthreads();
    for (int idx = t; idx < 5184; idx += 256){
      int rs = idx >> 6;            // 0..80
      int c  = idx & 63;
      Abf[(size_t)o * 20736 + rs * 256 + cc0 + c] = __float2bfloat16(wbuf[c * 81 + rs]);
    }
  }
}

// conv2 implicit GEMM: caps[b][o][pos] = sum_{c,r,s} w[o][c][r,s]*h[b][c][2y+r][2x+s]
// block = 1 batch; 4 waves x 64 o; N = 48 (36 valid pos); K-step = 32 c @ fixed rs.
__global__ __launch_bounds__(256) void conv2_mfma_kernel(
    const __hip_bfloat16* __restrict__ hbf, const __hip_bfloat16* __restrict__ Abf,
    const float* __restrict__ bias, float* __restrict__ caps){
  __shared__ ushort img[400 * 40];   // [pos 400][c 32 (+8 pad)] bf16, 32 KB
  int b = blockIdx.x;
  int t = threadIdx.x;
  int lane = t & 63;
  int wid  = t >> 6;           // 0..3
  int l15  = lane & 15;
  int quad = lane >> 4;        // 0..3
  int o_w  = wid * 64;

  // B-frag base row index per fn (n = fn*16 + l15 -> (y,x) -> 2y*20+2x)
  int bn[3];
  #pragma unroll
  for (int fn = 0; fn < 3; fn++){
    int n = fn * 16 + l15;
    int y = n / 6, x = n - y * 6;
    bn[fn] = (n < 36) ? (2 * y * 20 + 2 * x) : 0;
  }

  // A row pointers (short8 granular): row o, column quad*8
  const short8* arow[4];
  #pragma unroll
  for (int fo = 0; fo < 4; fo++){
    int o = o_w + fo * 16 + l15;
    arow[fo] = (const short8*)Abf + (size_t)o * 2592 + quad;
  }
  const short8* img8 = (const short8*)img;

  float4v acc[4][3];
  #pragma unroll
  for (int fo = 0; fo < 4; fo++)
    #pragma unroll
    for (int fn = 0; fn < 3; fn++)
      acc[fo][fn] = (float4v){0.f, 0.f, 0.f, 0.f};

  const __hip_bfloat16* hb = hbf + (size_t)b * 102400;   // 256*400

  for (int ct = 0; ct < 8; ct++){
    __syncthreads();
    // stage image tile: 32 c x 400 pos -> LDS [pos][c] (row stride 40)
    for (int idx = t; idx < 6400; idx += 256){
      int cc = idx / 200;
      int pp = (idx - cc * 200) * 2;
      unsigned u = *(const unsigned*)(hb + (size_t)(ct * 32 + cc) * 400 + pp);
      img[pp * 40 + cc]       = (ushort)(u & 0xffffu);
      img[(pp + 1) * 40 + cc] = (ushort)(u >> 16);
    }
    __syncthreads();
    int c0d8 = ct * 4;   // (ct*32)/8

    for (int r = 0; r < 9; r++){
      #pragma unroll
      for (int s = 0; s < 9; s++){
        int rs = r * 9 + s;
        int roff = r * 20 + s;
        short8 a[4], bf[3];
        #pragma unroll
        for (int fo = 0; fo < 4; fo++) a[fo] = arow[fo][rs * 32 + c0d8];
        #pragma unroll
        for (int fn = 0; fn < 3; fn++) bf[fn] = img8[(bn[fn] + roff) * 5 + quad];
        #pragma unroll
        for (int fo = 0; fo < 4; fo++)
          #pragma unroll
          for (int fn = 0; fn < 3; fn++)
            acc[fo][fn] = __builtin_amdgcn_mfma_f32_16x16x32_bf16(a[fo], bf[fn], acc[fo][fn], 0, 0, 0);
      }
    }
  }

  // epilogue: D row = o (quad*4+reg), col = pos (l15)
  float* cb = caps + (size_t)b * 9216;
  #pragma unroll
  for (int fo = 0; fo < 4; fo++){
    int ob = o_w + fo * 16 + quad * 4;
    #pragma unroll
    for (int fn = 0; fn < 3; fn++){
      int pos = fn * 16 + l15;
      if (pos < 36){
        #pragma unroll
        for (int rr = 0; rr < 4; rr++)
          cb[(size_t)(ob + rr) * 36 + pos] = acc[fo][fn][rr] + bias[ob + rr];
      }
    }
  }
}

// in-place squash over last dim of caps [256*1152, 8]
__global__ __launch_bounds__(256) void squash_kernel(float* __restrict__ caps){
  size_t cid = (size_t)blockIdx.x * 256 + threadIdx.x;   // exactly 294912
  float4* p = (float4*)(caps + cid * 8);
  float4 a = p[0], b4 = p[1];
  float msq = a.x*a.x + a.y*a.y + a.z*a.z + a.w*a.w
            + b4.x*b4.x + b4.y*b4.y + b4.z*b4.z + b4.w*b4.w;
  float scale = sqrtf(msq) / (1.f + msq);
  a.x *= scale; a.y *= scale; a.z *= scale; a.w *= scale;
  b4.x *= scale; b4.y *= scale; b4.z *= scale; b4.w *= scale;
  p[0] = a; p[1] = b4;
}

// u_hat[b,i,jd] = sum_k W[i,jd,k]*caps[b,i,k]  -> bf16, layout [b][i][160]
__global__ __launch_bounds__(256) void uhat_kernel(const float* __restrict__ caps,
    const float* __restrict__ Wt, __hip_bfloat16* __restrict__ uh){
  __shared__ float cl[4096];   // [16 b][32 i][8 k]
  int i0 = blockIdx.x * 32;
  int b0 = blockIdx.y * 16;
  int t = threadIdx.x;
  for (int idx = t; idx < 4096; idx += 256){
    int b_l = idx >> 8;
    int rest = idx & 255;
    cl[idx] = caps[((size_t)(b0 + b_l) * 1152 + i0 + (rest >> 3)) * 8 + (rest & 7)];
  }
  __syncthreads();
  int wid = t >> 6, l = t & 63;
  for (int ii = 0; ii < 8; ii++){
    int i = i0 + ii * 4 + wid;
    float wreg[3][8];
    #pragma unroll
    for (int m = 0; m < 3; m++){
      int jd = m * 64 + l;
      if (jd < 160){
        const float4* wp = (const float4*)&Wt[((size_t)i * 160 + jd) * 8];
        float4 p0 = wp[0], p1 = wp[1];
        wreg[m][0]=p0.x; wreg[m][1]=p0.y; wreg[m][2]=p0.z; wreg[m][3]=p0.w;
        wreg[m][4]=p1.x; wreg[m][5]=p1.y; wreg[m][6]=p1.z; wreg[m][7]=p1.w;
      }
    }
    for (int b_l = 0; b_l < 16; b_l++){
      const float4* cp4 = (const float4*)&cl[(b_l * 32 + ii * 4 + wid) * 8];
      float4 ca = cp4[0], cb = cp4[1];
      float ck[8] = {ca.x, ca.y, ca.z, ca.w, cb.x, cb.y, cb.z, cb.w};
      size_t ubase = ((size_t)(b0 + b_l) * 1152 + i) * 160;
      #pragma unroll
      for (int m = 0; m < 3; m++){
        int jd = m * 64 + l;
        if (jd < 160){
          float uv = 0.f;
          #pragma unroll
          for (int k = 0; k < 8; k++) uv = fmaf(wreg[m][k], ck[k], uv);
          uh[ubase + jd] = __float2bfloat16(uv);
        }
      }
    }
  }
}

// route A: b_ij (+)= u.v ; c = softmax_j(b)
__global__ __launch_bounds__(128) void routeA_kernel(const __hip_bfloat16* __restrict__ u,
    const float* __restrict__ v, float* __restrict__ bbuf, float* __restrict__ cbuf,
    int first){
  __shared__ float vs[160];
  int b = blockIdx.x;
  int ig = blockIdx.y;
  int t = threadIdx.x;
  for (int idx = t; idx < 160; idx += 128) vs[idx] = v[b * 160 + idx];
  __syncthreads();
  int i = ig * 128 + t;
  const __hip_bfloat16* up = u + ((size_t)b * 1152 + i) * 160;
  float dots[10];
  #pragma unroll
  for (int j = 0; j < 10; j++){
    const uint4* q = (const uint4*)(up + j * 16);
    uint4 a = q[0], b2 = q[1];
    unsigned wv[8] = {a.x, a.y, a.z, a.w, b2.x, b2.y, b2.z, b2.w};
    const float* vj = &vs[j * 16];
    float d0 = 0.f;
    #pragma unroll
    for (int wq = 0; wq < 8; wq++){
      d0 = fmaf(bf_lo(wv[wq]), vj[2*wq],   d0);
      d0 = fmaf(bf_hi(wv[wq]), vj[2*wq+1], d0);
    }
    dots[j] = d0;
  }
  float* bp = bbuf + (size_t)b * 11520 + i;
  if (!first){
    #pragma unroll
    for (int j = 0; j < 10; j++) dots[j] += bp[j * 1152];
  }
  #pragma unroll
  for (int j = 0; j < 10; j++) bp[j * 1152] = dots[j];
  float mx = dots[0];
  #pragma unroll
  for (int j = 1; j < 10; j++) mx = fmaxf(mx, dots[j]);
  float e[10]; float se = 0.f;
  #pragma unroll
  for (int j = 0; j < 10; j++){ e[j] = __expf(dots[j] - mx); se += e[j]; }
  float inv = 1.f / se;
  float* cp = cbuf + (size_t)b * 11520 + i;
  #pragma unroll
  for (int j = 0; j < 10; j++) cp[j * 1152] = e[j] * inv;
}

// route B: s[jd] = sum_i c[i,j]*u[i,jd] (+bias) ; v = squash_d(s)
__global__ __launch_bounds__(320) void routeB_kernel(const __hip_bfloat16* __restrict__ u,
    const float* __restrict__ cbuf, const float* __restrict__ dcb,
    float* __restrict__ vout, int mode){
  __shared__ float sp[2][160];
  int b = blockIdx.x;
  int t = threadIdx.x;
  int ipar = t / 160;
  int jd = t - ipar * 160;
  int j = jd >> 4;
  const __hip_bfloat16* up = u + (size_t)b * 184320 + jd;
  const float* cp = cbuf + (size_t)b * 11520 + (size_t)j * 1152;
  float s = 0.f;
  if (mode){
    #pragma unroll 8
    for (int i = ipar; i < 1152; i += 2){
      float uv = __bfloat162float(up[(size_t)i * 160]);
      s = fmaf(uv, cp[i], s);
    }
  } else {
    #pragma unroll 8
    for (int i = ipar; i < 1152; i += 2){
      float uv = __bfloat162float(up[(size_t)i * 160]);
      s = fmaf(uv, 0.1f, s);
    }
  }
  sp[ipar][jd] = s;
  __syncthreads();
  if (t < 160){
    float sv = sp[0][t] + sp[1][t] + dcb[t];
    float msq = sv * sv;
    #pragma unroll
    for (int off = 1; off < 16; off <<= 1) msq += __shfl_xor(msq, off);
    float scale = sqrtf(msq) / (1.f + msq);
    vout[b * 160 + t] = sv * scale;
  }
}

extern "C" void kernel_launch(void* const* d_in, const int* in_sizes, int n_in,
                              void* d_out, int out_size, void* d_ws, size_t ws_size,
                              hipStream_t stream){
  (void)in_sizes; (void)n_in; (void)out_size; (void)ws_size;
  const float* x   = (const float*)d_in[0];
  const float* w1  = (const float*)d_in[1];
  const float* b1  = (const float*)d_in[2];
  const float* w2  = (const float*)d_in[3];
  const float* b2  = (const float*)d_in[4];
  const float* W   = (const float*)d_in[5];
  const float* dcb = (const float*)d_in[6];
  float* out = (float*)d_out;

  char* ws = (char*)d_ws;
  __hip_bfloat16* hbf = (__hip_bfloat16*)(ws);
  __hip_bfloat16* Abf = (__hip_bfloat16*)(ws + 52428800);
  __hip_bfloat16* uh  = (__hip_bfloat16*)(ws);            // overlays hbf/Abf (dead)
  float* caps = (float*)(ws + 94371840);
  float* bbuf = (float*)(ws + 103809024);
  float* cbuf = (float*)(ws + 115605504);
  float* vbuf = (float*)(ws + 127401984);

  conv1_kernel<<<dim3(256, 16), 320, 0, stream>>>(x, w1, b1, hbf);
  arepack_kernel<<<256, 256, 0, stream>>>(w2, Abf);
  conv2_mfma_kernel<<<256, 256, 0, stream>>>(hbf, Abf, b2, caps);
  squash_kernel<<<1152, 256, 0, stream>>>(caps);
  uhat_kernel<<<dim3(36, 16), 256, 0, stream>>>(caps, W, uh);
  routeB_kernel<<<256, 320, 0, stream>>>(uh, cbuf, dcb, vbuf, 0);
  routeA_kernel<<<dim3(256, 9), 128, 0, stream>>>(uh, vbuf, bbuf, cbuf, 1);
  routeB_kernel<<<256, 320, 0, stream>>>(uh, cbuf, dcb, vbuf, 1);
  routeA_kernel<<<dim3(256, 9), 128, 0, stream>>>(uh, vbuf, bbuf, cbuf, 0);
  routeB_kernel<<<256, 320, 0, stream>>>(uh, cbuf, dcb, out, 1);
}

// Round 3
// 664.334 us; speedup vs baseline: 3.7323x; 1.2648x over previous
//
#include <hip/hip_runtime.h>
#include <hip/hip_bf16.h>

// ---------------------------------------------------------------------------
// CapsuleNet forward. Round 3: conv2 occupancy fix (K-split x4, 16 waves/CU),
// conv1 writes transposed h_t[b][pos][c], conflict-free b128 staging.
//
// Workspace layout (bytes), total ~127.6 MB:
//   h_t  @ 0          : 256*400*256 bf16 = 52,428,800   (conv phase)
//   Abf  @ 52,428,800 : 256*20736 bf16   = 10,616,832
//   u_hat @ 0         : 256*1152*160 bf16 = 94,371,840  (overlays h_t/Abf)
//   caps @ 94,371,840 : 256*1152*8 f32 = 9,437,184
//   bbuf @ 103,809,024: 11,796,480
//   cbuf @ 115,605,504: 11,796,480
//   vbuf @ 127,401,984: 163,840
// ---------------------------------------------------------------------------

typedef __attribute__((ext_vector_type(8))) short short8;
typedef __attribute__((ext_vector_type(4))) float float4v;

__device__ inline float bf_lo(unsigned u){ return __uint_as_float(u << 16); }
__device__ inline float bf_hi(unsigned u){ return __uint_as_float(u & 0xffff0000u); }

// conv1: x[256,1,28,28] * w[256,1,9,9] -> h_t[b][pos 400][c 256] bf16
__global__ __launch_bounds__(320) void conv1_kernel(const float* __restrict__ x,
    const float* __restrict__ w, const float* __restrict__ bias,
    __hip_bfloat16* __restrict__ ht){
  __shared__ float img[784];
  __shared__ float wsv[16 * 81];
  __shared__ ushort tile[400 * 18];   // [pos][o 16 (+2 pad)]
  int b = blockIdx.x;
  int og = blockIdx.y;
  int t = threadIdx.x;
  const float* xb = x + (size_t)b * 784;
  for (int idx = t; idx < 784; idx += 320) img[idx] = xb[idx];
  for (int idx = t; idx < 1296; idx += 320) wsv[idx] = w[(size_t)og * 1296 + idx];
  __syncthreads();
  int o_l = t / 20;        // 0..15
  int y   = t - o_l * 20;  // 0..19
  float acc[20];
  #pragma unroll
  for (int i = 0; i < 20; i++) acc[i] = 0.f;
  #pragma unroll
  for (int r = 0; r < 9; r++){
    float row[28];
    const float4* rp = (const float4*)&img[(y + r) * 28];
    #pragma unroll
    for (int q = 0; q < 7; q++){
      float4 v4 = rp[q];
      row[4*q+0]=v4.x; row[4*q+1]=v4.y; row[4*q+2]=v4.z; row[4*q+3]=v4.w;
    }
    #pragma unroll
    for (int s = 0; s < 9; s++){
      float wv = wsv[o_l * 81 + r * 9 + s];
      #pragma unroll
      for (int xx = 0; xx < 20; xx++)
        acc[xx] = fmaf(wv, row[xx + s], acc[xx]);
    }
  }
  float bv = bias[og * 16 + o_l];
  #pragma unroll
  for (int xx = 0; xx < 20; xx++){
    __hip_bfloat16 hv = __float2bfloat16(acc[xx] + bv);
    tile[(y * 20 + xx) * 18 + o_l] = *(ushort*)&hv;
  }
  __syncthreads();
  // write out: h_t[b][pos][og*16 + 0..15], 4B per lane
  __hip_bfloat16* hb = ht + (size_t)b * 102400 + og * 16;
  for (int idx = t; idx < 3200; idx += 320){
    int pos = idx >> 3, op = idx & 7;
    unsigned v = *(const unsigned*)&tile[pos * 18 + op * 2];
    *(unsigned*)(hb + (size_t)pos * 256 + op * 2) = v;
  }
}

// repack conv2 weights: Abf[o][k], k = (r*9+s)*256 + c  (bf16)
__global__ __launch_bounds__(256) void arepack_kernel(const float* __restrict__ w2,
    __hip_bfloat16* __restrict__ Abf){
  __shared__ float wbuf[64 * 81];
  int o = blockIdx.x;
  int t = threadIdx.x;
  for (int cc0 = 0; cc0 < 256; cc0 += 64){
    __syncthreads();
    for (int idx = t; idx < 5184; idx += 256)
      wbuf[idx] = w2[(size_t)o * 20736 + (size_t)cc0 * 81 + idx];
    __syncthreads();
    for (int idx = t; idx < 5184; idx += 256){
      int rs = idx >> 6;
      int c  = idx & 63;
      Abf[(size_t)o * 20736 + rs * 256 + cc0 + c] = __float2bfloat16(wbuf[c * 81 + rs]);
    }
  }
}

// caps[b][o][pos] = bias[o]  (conv2 accumulates on top with atomics)
__global__ __launch_bounds__(256) void capsinit_kernel(const float* __restrict__ bias,
    float* __restrict__ caps){
  int i = blockIdx.x * 256 + threadIdx.x;   // 2,359,296 total
  int rem = i % 9216;
  caps[i] = bias[rem / 36];
}

// conv2 implicit GEMM, K-split x4: block=(image b, k-quarter cq), 2 c-tiles each.
__global__ __launch_bounds__(256, 4) void conv2_mfma_kernel(
    const __hip_bfloat16* __restrict__ ht, const __hip_bfloat16* __restrict__ Abf,
    float* __restrict__ caps){
  __shared__ ushort img[400 * 40];   // [pos 400][c 32 (+8 pad)] bf16, 32 KB
  int b  = blockIdx.x;
  int cq = blockIdx.y;   // 0..3
  int t = threadIdx.x;
  int lane = t & 63;
  int wid  = t >> 6;
  int l15  = lane & 15;
  int quad = lane >> 4;
  int o_w  = wid * 64;

  int bn[3];
  #pragma unroll
  for (int fn = 0; fn < 3; fn++){
    int n = fn * 16 + l15;
    int y = n / 6, x = n - y * 6;
    bn[fn] = (n < 36) ? (2 * y * 20 + 2 * x) : 0;
  }

  const short8* arow[4];
  #pragma unroll
  for (int fo = 0; fo < 4; fo++){
    int o = o_w + fo * 16 + l15;
    arow[fo] = (const short8*)Abf + (size_t)o * 2592 + quad;
  }
  const short8* img8 = (const short8*)img;

  float4v acc[4][3];
  #pragma unroll
  for (int fo = 0; fo < 4; fo++)
    #pragma unroll
    for (int fn = 0; fn < 3; fn++)
      acc[fo][fn] = (float4v){0.f, 0.f, 0.f, 0.f};

  const __hip_bfloat16* hb = ht + (size_t)b * 102400;

  for (int ci = 0; ci < 2; ci++){
    int ct = cq * 2 + ci;
    __syncthreads();
    // stage [pos][c] tile: 16B load + 16B LDS store per lane, conflict-light
    for (int idx = t; idx < 1600; idx += 256){
      int p = idx >> 2, q = idx & 3;
      uint4 v = *(const uint4*)(hb + (size_t)p * 256 + ct * 32 + q * 8);
      *(uint4*)&img[p * 40 + q * 8] = v;
    }
    __syncthreads();
    int c0d8 = ct * 4;

    for (int r = 0; r < 9; r++){
      #pragma unroll
      for (int s = 0; s < 9; s++){
        int rs = r * 9 + s;
        int roff = r * 20 + s;
        short8 a[4], bf[3];
        #pragma unroll
        for (int fo = 0; fo < 4; fo++) a[fo] = arow[fo][rs * 32 + c0d8];
        #pragma unroll
        for (int fn = 0; fn < 3; fn++) bf[fn] = img8[(bn[fn] + roff) * 5 + quad];
        #pragma unroll
        for (int fo = 0; fo < 4; fo++)
          #pragma unroll
          for (int fn = 0; fn < 3; fn++)
            acc[fo][fn] = __builtin_amdgcn_mfma_f32_16x16x32_bf16(a[fo], bf[fn], acc[fo][fn], 0, 0, 0);
      }
    }
  }

  float* cb = caps + (size_t)b * 9216;
  #pragma unroll
  for (int fo = 0; fo < 4; fo++){
    int ob = o_w + fo * 16 + quad * 4;
    #pragma unroll
    for (int fn = 0; fn < 3; fn++){
      int pos = fn * 16 + l15;
      if (pos < 36){
        #pragma unroll
        for (int rr = 0; rr < 4; rr++)
          atomicAdd(&cb[(size_t)(ob + rr) * 36 + pos], acc[fo][fn][rr]);
      }
    }
  }
}

// in-place squash over last dim of caps [256*1152, 8]
__global__ __launch_bounds__(256) void squash_kernel(float* __restrict__ caps){
  size_t cid = (size_t)blockIdx.x * 256 + threadIdx.x;
  float4* p = (float4*)(caps + cid * 8);
  float4 a = p[0], b4 = p[1];
  float msq = a.x*a.x + a.y*a.y + a.z*a.z + a.w*a.w
            + b4.x*b4.x + b4.y*b4.y + b4.z*b4.z + b4.w*b4.w;
  float scale = sqrtf(msq) / (1.f + msq);
  a.x *= scale; a.y *= scale; a.z *= scale; a.w *= scale;
  b4.x *= scale; b4.y *= scale; b4.z *= scale; b4.w *= scale;
  p[0] = a; p[1] = b4;
}

// u_hat[b,i,jd] = sum_k W[i,jd,k]*caps[b,i,k]  -> bf16, layout [b][i][160]
__global__ __launch_bounds__(256) void uhat_kernel(const float* __restrict__ caps,
    const float* __restrict__ Wt, __hip_bfloat16* __restrict__ uh){
  __shared__ float cl[4096];
  int i0 = blockIdx.x * 32;
  int b0 = blockIdx.y * 16;
  int t = threadIdx.x;
  for (int idx = t; idx < 4096; idx += 256){
    int b_l = idx >> 8;
    int rest = idx & 255;
    cl[idx] = caps[((size_t)(b0 + b_l) * 1152 + i0 + (rest >> 3)) * 8 + (rest & 7)];
  }
  __syncthreads();
  int wid = t >> 6, l = t & 63;
  for (int ii = 0; ii < 8; ii++){
    int i = i0 + ii * 4 + wid;
    float wreg[3][8];
    #pragma unroll
    for (int m = 0; m < 3; m++){
      int jd = m * 64 + l;
      if (jd < 160){
        const float4* wp = (const float4*)&Wt[((size_t)i * 160 + jd) * 8];
        float4 p0 = wp[0], p1 = wp[1];
        wreg[m][0]=p0.x; wreg[m][1]=p0.y; wreg[m][2]=p0.z; wreg[m][3]=p0.w;
        wreg[m][4]=p1.x; wreg[m][5]=p1.y; wreg[m][6]=p1.z; wreg[m][7]=p1.w;
      }
    }
    for (int b_l = 0; b_l < 16; b_l++){
      const float4* cp4 = (const float4*)&cl[(b_l * 32 + ii * 4 + wid) * 8];
      float4 ca = cp4[0], cb = cp4[1];
      float ck[8] = {ca.x, ca.y, ca.z, ca.w, cb.x, cb.y, cb.z, cb.w};
      size_t ubase = ((size_t)(b0 + b_l) * 1152 + i) * 160;
      #pragma unroll
      for (int m = 0; m < 3; m++){
        int jd = m * 64 + l;
        if (jd < 160){
          float uv = 0.f;
          #pragma unroll
          for (int k = 0; k < 8; k++) uv = fmaf(wreg[m][k], ck[k], uv);
          uh[ubase + jd] = __float2bfloat16(uv);
        }
      }
    }
  }
}

// route A: b_ij (+)= u.v ; c = softmax_j(b)
__global__ __launch_bounds__(128) void routeA_kernel(const __hip_bfloat16* __restrict__ u,
    const float* __restrict__ v, float* __restrict__ bbuf, float* __restrict__ cbuf,
    int first){
  __shared__ float vs[160];
  int b = blockIdx.x;
  int ig = blockIdx.y;
  int t = threadIdx.x;
  for (int idx = t; idx < 160; idx += 128) vs[idx] = v[b * 160 + idx];
  __syncthreads();
  int i = ig * 128 + t;
  const __hip_bfloat16* up = u + ((size_t)b * 1152 + i) * 160;
  float dots[10];
  #pragma unroll
  for (int j = 0; j < 10; j++){
    const uint4* q = (const uint4*)(up + j * 16);
    uint4 a = q[0], b2 = q[1];
    unsigned wv[8] = {a.x, a.y, a.z, a.w, b2.x, b2.y, b2.z, b2.w};
    const float* vj = &vs[j * 16];
    float d0 = 0.f;
    #pragma unroll
    for (int wq = 0; wq < 8; wq++){
      d0 = fmaf(bf_lo(wv[wq]), vj[2*wq],   d0);
      d0 = fmaf(bf_hi(wv[wq]), vj[2*wq+1], d0);
    }
    dots[j] = d0;
  }
  float* bp = bbuf + (size_t)b * 11520 + i;
  if (!first){
    #pragma unroll
    for (int j = 0; j < 10; j++) dots[j] += bp[j * 1152];
  }
  #pragma unroll
  for (int j = 0; j < 10; j++) bp[j * 1152] = dots[j];
  float mx = dots[0];
  #pragma unroll
  for (int j = 1; j < 10; j++) mx = fmaxf(mx, dots[j]);
  float e[10]; float se = 0.f;
  #pragma unroll
  for (int j = 0; j < 10; j++){ e[j] = __expf(dots[j] - mx); se += e[j]; }
  float inv = 1.f / se;
  float* cp = cbuf + (size_t)b * 11520 + i;
  #pragma unroll
  for (int j = 0; j < 10; j++) cp[j * 1152] = e[j] * inv;
}

// route B: s[jd] = sum_i c[i,j]*u[i,jd] (+bias) ; v = squash_d(s)
__global__ __launch_bounds__(320) void routeB_kernel(const __hip_bfloat16* __restrict__ u,
    const float* __restrict__ cbuf, const float* __restrict__ dcb,
    float* __restrict__ vout, int mode){
  __shared__ float sp[2][160];
  int b = blockIdx.x;
  int t = threadIdx.x;
  int ipar = t / 160;
  int jd = t - ipar * 160;
  int j = jd >> 4;
  const __hip_bfloat16* up = u + (size_t)b * 184320 + jd;
  const float* cp = cbuf + (size_t)b * 11520 + (size_t)j * 1152;
  float s = 0.f;
  if (mode){
    #pragma unroll 8
    for (int i = ipar; i < 1152; i += 2){
      float uv = __bfloat162float(up[(size_t)i * 160]);
      s = fmaf(uv, cp[i], s);
    }
  } else {
    #pragma unroll 8
    for (int i = ipar; i < 1152; i += 2){
      float uv = __bfloat162float(up[(size_t)i * 160]);
      s = fmaf(uv, 0.1f, s);
    }
  }
  sp[ipar][jd] = s;
  __syncthreads();
  if (t < 160){
    float sv = sp[0][t] + sp[1][t] + dcb[t];
    float msq = sv * sv;
    #pragma unroll
    for (int off = 1; off < 16; off <<= 1) msq += __shfl_xor(msq, off);
    float scale = sqrtf(msq) / (1.f + msq);
    vout[b * 160 + t] = sv * scale;
  }
}

extern "C" void kernel_launch(void* const* d_in, const int* in_sizes, int n_in,
                              void* d_out, int out_size, void* d_ws, size_t ws_size,
                              hipStream_t stream){
  (void)in_sizes; (void)n_in; (void)out_size; (void)ws_size;
  const float* x   = (const float*)d_in[0];
  const float* w1  = (const float*)d_in[1];
  const float* b1  = (const float*)d_in[2];
  const float* w2  = (const float*)d_in[3];
  const float* b2  = (const float*)d_in[4];
  const float* W   = (const float*)d_in[5];
  const float* dcb = (const float*)d_in[6];
  float* out = (float*)d_out;

  char* ws = (char*)d_ws;
  __hip_bfloat16* ht  = (__hip_bfloat16*)(ws);
  __hip_bfloat16* Abf = (__hip_bfloat16*)(ws + 52428800);
  __hip_bfloat16* uh  = (__hip_bfloat16*)(ws);            // overlays ht/Abf (dead)
  float* caps = (float*)(ws + 94371840);
  float* bbuf = (float*)(ws + 103809024);
  float* cbuf = (float*)(ws + 115605504);
  float* vbuf = (float*)(ws + 127401984);

  conv1_kernel<<<dim3(256, 16), 320, 0, stream>>>(x, w1, b1, ht);
  arepack_kernel<<<256, 256, 0, stream>>>(w2, Abf);
  capsinit_kernel<<<9216, 256, 0, stream>>>(b2, caps);
  conv2_mfma_kernel<<<dim3(256, 4), 256, 0, stream>>>(ht, Abf, caps);
  squash_kernel<<<1152, 256, 0, stream>>>(caps);
  uhat_kernel<<<dim3(36, 16), 256, 0, stream>>>(caps, W, uh);
  routeB_kernel<<<256, 320, 0, stream>>>(uh, cbuf, dcb, vbuf, 0);
  routeA_kernel<<<dim3(256, 9), 128, 0, stream>>>(uh, vbuf, bbuf, cbuf, 1);
  routeB_kernel<<<256, 320, 0, stream>>>(uh, cbuf, dcb, vbuf, 1);
  routeA_kernel<<<dim3(256, 9), 128, 0, stream>>>(uh, vbuf, bbuf, cbuf, 0);
  routeB_kernel<<<256, 320, 0, stream>>>(uh, cbuf, dcb, out, 1);
}

// Round 5
// 576.060 us; speedup vs baseline: 4.3042x; 1.1532x over previous
//
#include <hip/hip_runtime.h>
#include <hip/hip_bf16.h>

// ---------------------------------------------------------------------------
// CapsuleNet forward. Round 5: R4 structure with the staging-slot mod-5 bug
// fixed (sl = (q + 2*(p/20)) % 5 — R4 only reduced once, OOB for y_pos>=6).
//
// Workspace layout (bytes), total ~127.6 MB:
//   h_t  @ 0          : 256*400*256 bf16 = 52,428,800   (conv phase)
//   A2   @ 52,428,800 : 256*20736 bf16   = 10,616,832   (repacked, wave-tiled)
//   u_hat @ 0         : 256*1152*160 bf16 = 94,371,840  (overlays h_t/A2)
//   caps @ 94,371,840 : 9,437,184
//   bbuf @ 103,809,024: 11,796,480
//   cbuf @ 115,605,504: 11,796,480
//   vbuf @ 127,401,984: 163,840
// ---------------------------------------------------------------------------

typedef __attribute__((ext_vector_type(8))) short short8;
typedef __attribute__((ext_vector_type(4))) float float4v;

__device__ inline float bf_lo(unsigned u){ return __uint_as_float(u << 16); }
__device__ inline float bf_hi(unsigned u){ return __uint_as_float(u & 0xffff0000u); }

// conv1: x[256,1,28,28] * w[256,1,9,9] -> h_t[b][pos 400][c 256] bf16
__global__ __launch_bounds__(320) void conv1_kernel(const float* __restrict__ x,
    const float* __restrict__ w, const float* __restrict__ bias,
    __hip_bfloat16* __restrict__ ht){
  __shared__ float img[784];
  __shared__ float wsv[16 * 81];
  __shared__ ushort tile[400 * 18];   // [pos][o 16 (+2 pad)]
  int b = blockIdx.x;
  int og = blockIdx.y;
  int t = threadIdx.x;
  const float* xb = x + (size_t)b * 784;
  for (int idx = t; idx < 784; idx += 320) img[idx] = xb[idx];
  for (int idx = t; idx < 1296; idx += 320) wsv[idx] = w[(size_t)og * 1296 + idx];
  __syncthreads();
  int o_l = t / 20;        // 0..15
  int y   = t - o_l * 20;  // 0..19
  float acc[20];
  #pragma unroll
  for (int i = 0; i < 20; i++) acc[i] = 0.f;
  #pragma unroll
  for (int r = 0; r < 9; r++){
    float row[28];
    const float4* rp = (const float4*)&img[(y + r) * 28];
    #pragma unroll
    for (int q = 0; q < 7; q++){
      float4 v4 = rp[q];
      row[4*q+0]=v4.x; row[4*q+1]=v4.y; row[4*q+2]=v4.z; row[4*q+3]=v4.w;
    }
    #pragma unroll
    for (int s = 0; s < 9; s++){
      float wv = wsv[o_l * 81 + r * 9 + s];
      #pragma unroll
      for (int xx = 0; xx < 20; xx++)
        acc[xx] = fmaf(wv, row[xx + s], acc[xx]);
    }
  }
  float bv = bias[og * 16 + o_l];
  #pragma unroll
  for (int xx = 0; xx < 20; xx++){
    __hip_bfloat16 hv = __float2bfloat16(acc[xx] + bv);
    tile[(y * 20 + xx) * 18 + o_l] = *(ushort*)&hv;
  }
  __syncthreads();
  __hip_bfloat16* hb = ht + (size_t)b * 102400 + og * 16;
  for (int idx = t; idx < 3200; idx += 320){
    int pos = idx >> 3, op = idx & 7;
    unsigned v = *(const unsigned*)&tile[pos * 18 + op * 2];
    *(unsigned*)(hb + (size_t)pos * 256 + op * 2) = v;
  }
}

// repack conv2 weights into wave-tiled layout:
// A2 short8 index = ow*165888 + ct*256 + rs*2048 + fo*64 + l15*4 + quad
//   (o = ow*64 + fo*16 + l15; c = ct*32 + quad*8 + e)
__global__ __launch_bounds__(256) void arepack_kernel(const float* __restrict__ w2,
    ushort* __restrict__ A2s){
  __shared__ float wbuf[64 * 81];
  int o = blockIdx.x;
  int t = threadIdx.x;
  int ow = o >> 6, fo = (o >> 4) & 3, l15 = o & 15;
  size_t obase8 = (size_t)ow * 165888 + (size_t)fo * 64 + (size_t)l15 * 4;
  for (int c0 = 0; c0 < 256; c0 += 64){
    __syncthreads();
    for (int idx = t; idx < 5184; idx += 256)
      wbuf[idx] = w2[(size_t)o * 20736 + (size_t)c0 * 81 + idx];
    __syncthreads();
    for (int idx = t; idx < 2592; idx += 256){
      int rs = idx >> 5;
      int cp = (idx & 31) * 2;        // even local c
      int cg = c0 + cp;
      int ct = cg >> 5, quad = (cg >> 3) & 3, e = cg & 7;
      __hip_bfloat16 b0 = __float2bfloat16(wbuf[cp * 81 + rs]);
      __hip_bfloat16 b1 = __float2bfloat16(wbuf[(cp + 1) * 81 + rs]);
      unsigned pack = (unsigned)*(ushort*)&b0 | ((unsigned)*(ushort*)&b1 << 16);
      size_t si = (obase8 + (size_t)ct * 256 + (size_t)rs * 2048 + quad) * 8 + e;
      *(unsigned*)(A2s + si) = pack;
    }
  }
}

// caps[b][o][pos] = bias[o]  (conv2 accumulates on top with atomics)
__global__ __launch_bounds__(256) void capsinit_kernel(const float* __restrict__ bias,
    float* __restrict__ caps){
  int i = blockIdx.x * 256 + threadIdx.x;
  int rem = i % 9216;
  caps[i] = bias[rem / 36];
}

// conv2 implicit GEMM. Linear grid 1024; kq pinned per XCD (blockIdx%8).
__global__ __launch_bounds__(256, 4) void conv2_mfma_kernel(
    const __hip_bfloat16* __restrict__ ht, const short8* __restrict__ A2,
    float* __restrict__ caps){
  __shared__ ushort img[400 * 40];   // 80B rows, 5 x 16B slots, slot-rotated
  int bx  = blockIdx.x;
  int xcd = bx & 7;
  int kq  = xcd >> 1;                       // same kq for all blocks on this XCD
  int b   = ((bx >> 3) << 1) | (xcd & 1);   // image 0..255
  int t = threadIdx.x;
  int lane = t & 63;
  int wid  = t >> 6;
  int l15  = lane & 15;
  int quad = lane >> 4;

  // B-frag lane geometry: n = fn*16+l15 -> (y,x); row = 40y+2x (+20r+s)
  int bn[3], slc[3];
  #pragma unroll
  for (int fn = 0; fn < 3; fn++){
    int n = fn * 16 + l15;
    int y = n / 6, xx = n - y * 6;
    if (n >= 36){ y = 0; xx = 0; }
    bn[fn]  = 40 * y + 2 * xx;
    slc[fn] = (quad + 4 * y) % 5;    // slot base; +2r (mod 5) per r
  }

  const short8* img8 = (const short8*)img;

  float4v acc[4][3];
  #pragma unroll
  for (int fo = 0; fo < 4; fo++)
    #pragma unroll
    for (int fn = 0; fn < 3; fn++)
      acc[fo][fn] = (float4v){0.f, 0.f, 0.f, 0.f};

  const __hip_bfloat16* hb = ht + (size_t)b * 102400;

  for (int ci = 0; ci < 2; ci++){
    int ct = kq * 2 + ci;
    __syncthreads();
    // stage 32c x 400pos tile; chunk q of row p stored at slot (q+2*(p/20))%5
    for (int idx = t; idx < 1600; idx += 256){
      int p = idx >> 2, q = idx & 3;
      int sl = (q + 2 * (p / 20)) % 5;     // R4 bug fix: true mod-5
      uint4 v = *(const uint4*)(hb + (size_t)p * 256 + ct * 32 + q * 8);
      *(uint4*)&img[p * 40 + sl * 8] = v;
    }
    __syncthreads();

    const short8* ap = A2 + ((size_t)wid * 648 + ct) * 256 + l15 * 4 + quad;

    short8 aF[2][4], bF[2][3];
    // prologue: rs=0 (r=0,s=0)
    #pragma unroll
    for (int fo = 0; fo < 4; fo++) aF[0][fo] = ap[fo * 64];
    #pragma unroll
    for (int fn = 0; fn < 3; fn++) bF[0][fn] = img8[bn[fn] * 5 + slc[fn]];

    int rn = 0, sn = 0, r2m = 0;   // r2m = (2*rn) % 5
    #pragma unroll 2
    for (int rs = 0; rs < 81; rs++){
      int cur = rs & 1, nxt = cur ^ 1;
      // advance to next (r,s)
      sn++;
      if (sn == 9){ sn = 0; rn++; r2m += 2; if (r2m >= 5) r2m -= 5; }
      int nrs = (rs < 80) ? rs + 1 : 80;
      int roff = rn * 20 + sn;
      const short8* apn = ap + (size_t)nrs * 2048;
      #pragma unroll
      for (int fo = 0; fo < 4; fo++) aF[nxt][fo] = apn[fo * 64];
      #pragma unroll
      for (int fn = 0; fn < 3; fn++){
        int sl = slc[fn] + r2m; if (sl >= 5) sl -= 5;
        bF[nxt][fn] = img8[(bn[fn] + roff) * 5 + sl];
      }
      #pragma unroll
      for (int fo = 0; fo < 4; fo++)
        #pragma unroll
        for (int fn = 0; fn < 3; fn++)
          acc[fo][fn] = __builtin_amdgcn_mfma_f32_16x16x32_bf16(aF[cur][fo], bF[cur][fn], acc[fo][fn], 0, 0, 0);
    }
  }

  float* cb = caps + (size_t)b * 9216;
  #pragma unroll
  for (int fo = 0; fo < 4; fo++){
    int ob = wid * 64 + fo * 16 + quad * 4;
    #pragma unroll
    for (int fn = 0; fn < 3; fn++){
      int pos = fn * 16 + l15;
      if (pos < 36){
        #pragma unroll
        for (int rr = 0; rr < 4; rr++)
          atomicAdd(&cb[(size_t)(ob + rr) * 36 + pos], acc[fo][fn][rr]);
      }
    }
  }
}

// in-place squash over last dim of caps [256*1152, 8]
__global__ __launch_bounds__(256) void squash_kernel(float* __restrict__ caps){
  size_t cid = (size_t)blockIdx.x * 256 + threadIdx.x;
  float4* p = (float4*)(caps + cid * 8);
  float4 a = p[0], b4 = p[1];
  float msq = a.x*a.x + a.y*a.y + a.z*a.z + a.w*a.w
            + b4.x*b4.x + b4.y*b4.y + b4.z*b4.z + b4.w*b4.w;
  float scale = sqrtf(msq) / (1.f + msq);
  a.x *= scale; a.y *= scale; a.z *= scale; a.w *= scale;
  b4.x *= scale; b4.y *= scale; b4.z *= scale; b4.w *= scale;
  p[0] = a; p[1] = b4;
}

// u_hat[b,i,jd] = sum_k W[i,jd,k]*caps[b,i,k]  -> bf16, layout [b][i][160]
__global__ __launch_bounds__(256) void uhat_kernel(const float* __restrict__ caps,
    const float* __restrict__ Wt, __hip_bfloat16* __restrict__ uh){
  __shared__ float cl[4096];
  int i0 = blockIdx.x * 32;
  int b0 = blockIdx.y * 16;
  int t = threadIdx.x;
  for (int idx = t; idx < 4096; idx += 256){
    int b_l = idx >> 8;
    int rest = idx & 255;
    cl[idx] = caps[((size_t)(b0 + b_l) * 1152 + i0 + (rest >> 3)) * 8 + (rest & 7)];
  }
  __syncthreads();
  int wid = t >> 6, l = t & 63;
  for (int ii = 0; ii < 8; ii++){
    int i = i0 + ii * 4 + wid;
    float wreg[3][8];
    #pragma unroll
    for (int m = 0; m < 3; m++){
      int jd = m * 64 + l;
      if (jd < 160){
        const float4* wp = (const float4*)&Wt[((size_t)i * 160 + jd) * 8];
        float4 p0 = wp[0], p1 = wp[1];
        wreg[m][0]=p0.x; wreg[m][1]=p0.y; wreg[m][2]=p0.z; wreg[m][3]=p0.w;
        wreg[m][4]=p1.x; wreg[m][5]=p1.y; wreg[m][6]=p1.z; wreg[m][7]=p1.w;
      }
    }
    for (int b_l = 0; b_l < 16; b_l++){
      const float4* cp4 = (const float4*)&cl[(b_l * 32 + ii * 4 + wid) * 8];
      float4 ca = cp4[0], cb = cp4[1];
      float ck[8] = {ca.x, ca.y, ca.z, ca.w, cb.x, cb.y, cb.z, cb.w};
      size_t ubase = ((size_t)(b0 + b_l) * 1152 + i) * 160;
      #pragma unroll
      for (int m = 0; m < 3; m++){
        int jd = m * 64 + l;
        if (jd < 160){
          float uv = 0.f;
          #pragma unroll
          for (int k = 0; k < 8; k++) uv = fmaf(wreg[m][k], ck[k], uv);
          uh[ubase + jd] = __float2bfloat16(uv);
        }
      }
    }
  }
}

// route A: b_ij (+)= u.v ; c = softmax_j(b)
__global__ __launch_bounds__(128) void routeA_kernel(const __hip_bfloat16* __restrict__ u,
    const float* __restrict__ v, float* __restrict__ bbuf, float* __restrict__ cbuf,
    int first){
  __shared__ float vs[160];
  int b = blockIdx.x;
  int ig = blockIdx.y;
  int t = threadIdx.x;
  for (int idx = t; idx < 160; idx += 128) vs[idx] = v[b * 160 + idx];
  __syncthreads();
  int i = ig * 128 + t;
  const __hip_bfloat16* up = u + ((size_t)b * 1152 + i) * 160;
  float dots[10];
  #pragma unroll
  for (int j = 0; j < 10; j++){
    const uint4* q = (const uint4*)(up + j * 16);
    uint4 a = q[0], b2 = q[1];
    unsigned wv[8] = {a.x, a.y, a.z, a.w, b2.x, b2.y, b2.z, b2.w};
    const float* vj = &vs[j * 16];
    float d0 = 0.f;
    #pragma unroll
    for (int wq = 0; wq < 8; wq++){
      d0 = fmaf(bf_lo(wv[wq]), vj[2*wq],   d0);
      d0 = fmaf(bf_hi(wv[wq]), vj[2*wq+1], d0);
    }
    dots[j] = d0;
  }
  float* bp = bbuf + (size_t)b * 11520 + i;
  if (!first){
    #pragma unroll
    for (int j = 0; j < 10; j++) dots[j] += bp[j * 1152];
  }
  #pragma unroll
  for (int j = 0; j < 10; j++) bp[j * 1152] = dots[j];
  float mx = dots[0];
  #pragma unroll
  for (int j = 1; j < 10; j++) mx = fmaxf(mx, dots[j]);
  float e[10]; float se = 0.f;
  #pragma unroll
  for (int j = 0; j < 10; j++){ e[j] = __expf(dots[j] - mx); se += e[j]; }
  float inv = 1.f / se;
  float* cp = cbuf + (size_t)b * 11520 + i;
  #pragma unroll
  for (int j = 0; j < 10; j++) cp[j * 1152] = e[j] * inv;
}

// route B: s[jd] = sum_i c[i,j]*u[i,jd] (+bias) ; v = squash_d(s)
__global__ __launch_bounds__(320) void routeB_kernel(const __hip_bfloat16* __restrict__ u,
    const float* __restrict__ cbuf, const float* __restrict__ dcb,
    float* __restrict__ vout, int mode){
  __shared__ float sp[2][160];
  int b = blockIdx.x;
  int t = threadIdx.x;
  int ipar = t / 160;
  int jd = t - ipar * 160;
  int j = jd >> 4;
  const __hip_bfloat16* up = u + (size_t)b * 184320 + jd;
  const float* cp = cbuf + (size_t)b * 11520 + (size_t)j * 1152;
  float s = 0.f;
  if (mode){
    #pragma unroll 8
    for (int i = ipar; i < 1152; i += 2){
      float uv = __bfloat162float(up[(size_t)i * 160]);
      s = fmaf(uv, cp[i], s);
    }
  } else {
    #pragma unroll 8
    for (int i = ipar; i < 1152; i += 2){
      float uv = __bfloat162float(up[(size_t)i * 160]);
      s = fmaf(uv, 0.1f, s);
    }
  }
  sp[ipar][jd] = s;
  __syncthreads();
  if (t < 160){
    float sv = sp[0][t] + sp[1][t] + dcb[t];
    float msq = sv * sv;
    #pragma unroll
    for (int off = 1; off < 16; off <<= 1) msq += __shfl_xor(msq, off);
    float scale = sqrtf(msq) / (1.f + msq);
    vout[b * 160 + t] = sv * scale;
  }
}

extern "C" void kernel_launch(void* const* d_in, const int* in_sizes, int n_in,
                              void* d_out, int out_size, void* d_ws, size_t ws_size,
                              hipStream_t stream){
  (void)in_sizes; (void)n_in; (void)out_size; (void)ws_size;
  const float* x   = (const float*)d_in[0];
  const float* w1  = (const float*)d_in[1];
  const float* b1  = (const float*)d_in[2];
  const float* w2  = (const float*)d_in[3];
  const float* b2  = (const float*)d_in[4];
  const float* W   = (const float*)d_in[5];
  const float* dcb = (const float*)d_in[6];
  float* out = (float*)d_out;

  char* ws = (char*)d_ws;
  __hip_bfloat16* ht  = (__hip_bfloat16*)(ws);
  ushort* A2s = (ushort*)(ws + 52428800);
  __hip_bfloat16* uh  = (__hip_bfloat16*)(ws);            // overlays ht/A2 (dead)
  float* caps = (float*)(ws + 94371840);
  float* bbuf = (float*)(ws + 103809024);
  float* cbuf = (float*)(ws + 115605504);
  float* vbuf = (float*)(ws + 127401984);

  conv1_kernel<<<dim3(256, 16), 320, 0, stream>>>(x, w1, b1, ht);
  arepack_kernel<<<256, 256, 0, stream>>>(w2, A2s);
  capsinit_kernel<<<9216, 256, 0, stream>>>(b2, caps);
  conv2_mfma_kernel<<<1024, 256, 0, stream>>>(ht, (const short8*)A2s, caps);
  squash_kernel<<<1152, 256, 0, stream>>>(caps);
  uhat_kernel<<<dim3(36, 16), 256, 0, stream>>>(caps, W, uh);
  routeB_kernel<<<256, 320, 0, stream>>>(uh, cbuf, dcb, vbuf, 0);
  routeA_kernel<<<dim3(256, 9), 128, 0, stream>>>(uh, vbuf, bbuf, cbuf, 1);
  routeB_kernel<<<256, 320, 0, stream>>>(uh, cbuf, dcb, vbuf, 1);
  routeA_kernel<<<dim3(256, 9), 128, 0, stream>>>(uh, vbuf, bbuf, cbuf, 0);
  routeB_kernel<<<256, 320, 0, stream>>>(uh, cbuf, dcb, out, 1);
}

// Round 6
// 473.591 us; speedup vs baseline: 5.2355x; 1.2164x over previous
//
#include <hip/hip_runtime.h>
#include <hip/hip_bf16.h>

// ---------------------------------------------------------------------------
// CapsuleNet forward. Round 6:
//  - conv2: 2 images/block (A-frag 2x reuse -> per-CU A L2-traffic halved),
//    plain-store epilogue into 4 per-kq partial buffers (no atomics).
//  - routing: fused dot+softmax+accumulate single-pass kernel, 3 launches
//    (u_hat read 3x instead of 5x), 20 waves/CU.
//  - conv1: 32-o blocks, full-line h_t writes.
//
// Workspace layout (bytes), total ~122.4 MB:
//   h_t   @ 0           : 256*400*256 bf16 = 52,428,800   (conv phase)
//   A2    @ 52,428,800  : 10,616,832  -> ends 63,045,632
//   caps4 @ 63,045,632  : 4*256*9216*4 = 37,748,736 -> ends 100,794,368
//   u_hat @ 0           : 94,371,840  (overlays h_t/A2/caps4 — all dead by uhat)
//   caps  @ 100,794,368 : 9,437,184   -> ends 110,231,552
//   bbuf  @ 110,231,552 : 256*1152*10*4 = 11,796,480 -> ends 122,028,032
//   vbuf  @ 122,028,032 : 163,840
// ---------------------------------------------------------------------------

typedef __attribute__((ext_vector_type(8))) short short8;
typedef __attribute__((ext_vector_type(4))) float float4v;

// conv1: x[256,1,28,28] * w[256,1,9,9] -> h_t[b][pos 400][c 256] bf16
__global__ __launch_bounds__(640) void conv1_kernel(const float* __restrict__ x,
    const float* __restrict__ w, const float* __restrict__ bias,
    __hip_bfloat16* __restrict__ ht){
  __shared__ float img[784];
  __shared__ float wsv[32 * 81];
  __shared__ ushort tile[400 * 33];   // [pos][o 32 (+1 pad)]
  int b = blockIdx.x;
  int og = blockIdx.y;                // 0..7 (32-o groups)
  int t = threadIdx.x;
  const float* xb = x + (size_t)b * 784;
  for (int idx = t; idx < 784; idx += 640) img[idx] = xb[idx];
  for (int idx = t; idx < 2592; idx += 640) wsv[idx] = w[(size_t)og * 2592 + idx];
  __syncthreads();
  int o_l = t / 20;        // 0..31
  int y   = t - o_l * 20;  // 0..19
  float acc[20];
  #pragma unroll
  for (int i = 0; i < 20; i++) acc[i] = 0.f;
  #pragma unroll
  for (int r = 0; r < 9; r++){
    float row[28];
    const float4* rp = (const float4*)&img[(y + r) * 28];
    #pragma unroll
    for (int q = 0; q < 7; q++){
      float4 v4 = rp[q];
      row[4*q+0]=v4.x; row[4*q+1]=v4.y; row[4*q+2]=v4.z; row[4*q+3]=v4.w;
    }
    #pragma unroll
    for (int s = 0; s < 9; s++){
      float wv = wsv[o_l * 81 + r * 9 + s];
      #pragma unroll
      for (int xx = 0; xx < 20; xx++)
        acc[xx] = fmaf(wv, row[xx + s], acc[xx]);
    }
  }
  float bv = bias[og * 32 + o_l];
  #pragma unroll
  for (int xx = 0; xx < 20; xx++){
    __hip_bfloat16 hv = __float2bfloat16(acc[xx] + bv);
    tile[(y * 20 + xx) * 33 + o_l] = *(ushort*)&hv;
  }
  __syncthreads();
  __hip_bfloat16* hb = ht + (size_t)b * 102400 + og * 32;
  for (int idx = t; idx < 6400; idx += 640){
    int pos = idx >> 4, op = idx & 15;
    unsigned v = (unsigned)tile[pos * 33 + op * 2]
               | ((unsigned)tile[pos * 33 + op * 2 + 1] << 16);
    *(unsigned*)(hb + (size_t)pos * 256 + op * 2) = v;
  }
}

// repack conv2 weights into wave-tiled layout:
// A2 short8 index = ow*165888 + ct*256 + rs*2048 + fo*64 + l15*4 + quad
__global__ __launch_bounds__(256) void arepack_kernel(const float* __restrict__ w2,
    ushort* __restrict__ A2s){
  __shared__ float wbuf[64 * 81];
  int o = blockIdx.x;
  int t = threadIdx.x;
  int ow = o >> 6, fo = (o >> 4) & 3, l15 = o & 15;
  size_t obase8 = (size_t)ow * 165888 + (size_t)fo * 64 + (size_t)l15 * 4;
  for (int c0 = 0; c0 < 256; c0 += 64){
    __syncthreads();
    for (int idx = t; idx < 5184; idx += 256)
      wbuf[idx] = w2[(size_t)o * 20736 + (size_t)c0 * 81 + idx];
    __syncthreads();
    for (int idx = t; idx < 2592; idx += 256){
      int rs = idx >> 5;
      int cp = (idx & 31) * 2;
      int cg = c0 + cp;
      int ct = cg >> 5, quad = (cg >> 3) & 3, e = cg & 7;
      __hip_bfloat16 b0 = __float2bfloat16(wbuf[cp * 81 + rs]);
      __hip_bfloat16 b1 = __float2bfloat16(wbuf[(cp + 1) * 81 + rs]);
      unsigned pack = (unsigned)*(ushort*)&b0 | ((unsigned)*(ushort*)&b1 << 16);
      size_t si = (obase8 + (size_t)ct * 256 + (size_t)rs * 2048 + quad) * 8 + e;
      *(unsigned*)(A2s + si) = pack;
    }
  }
}

// conv2 implicit GEMM, 2 images/block. Grid 512; kq pinned per XCD (bx%8).
// Writes per-kq partial caps4[kq][b][o*36+pos] (plain stores).
__global__ __launch_bounds__(256, 2) void conv2_mfma_kernel(
    const __hip_bfloat16* __restrict__ ht, const short8* __restrict__ A2,
    float* __restrict__ caps4){
  __shared__ ushort img[2][400 * 40];   // 64 KB, slot-rotated rows
  int bx  = blockIdx.x;
  int xcd = bx & 7;
  int kq  = xcd >> 1;
  int p   = ((bx >> 3) << 1) | (xcd & 1);   // pair 0..127
  int b0  = p * 2;
  int t = threadIdx.x;
  int lane = t & 63;
  int wid  = t >> 6;
  int l15  = lane & 15;
  int quad = lane >> 4;

  int bn[3], slc[3];
  #pragma unroll
  for (int fn = 0; fn < 3; fn++){
    int n = fn * 16 + l15;
    int y = n / 6, xx = n - y * 6;
    if (n >= 36){ y = 0; xx = 0; }
    bn[fn]  = 40 * y + 2 * xx;
    slc[fn] = (quad + 4 * y) % 5;
  }
  const short8* i0p = (const short8*)&img[0][0];
  const short8* i1p = (const short8*)&img[1][0];

  float4v acc[4][6];
  #pragma unroll
  for (int fo = 0; fo < 4; fo++)
    #pragma unroll
    for (int fn = 0; fn < 6; fn++)
      acc[fo][fn] = (float4v){0.f, 0.f, 0.f, 0.f};

  for (int ci = 0; ci < 2; ci++){
    int ct = kq * 2 + ci;
    __syncthreads();
    #pragma unroll
    for (int im = 0; im < 2; im++){
      const __hip_bfloat16* hb = ht + (size_t)(b0 + im) * 102400;
      for (int idx = t; idx < 1600; idx += 256){
        int pp = idx >> 2, q = idx & 3;
        int sl = (q + 2 * (pp / 20)) % 5;
        uint4 v = *(const uint4*)(hb + (size_t)pp * 256 + ct * 32 + q * 8);
        *(uint4*)&img[im][pp * 40 + sl * 8] = v;
      }
    }
    __syncthreads();

    const short8* ap = A2 + ((size_t)wid * 648 + ct) * 256 + l15 * 4 + quad;

    short8 aF[2][4], bF[2][6];
    #pragma unroll
    for (int fo = 0; fo < 4; fo++) aF[0][fo] = ap[fo * 64];
    #pragma unroll
    for (int fn = 0; fn < 6; fn++){
      int f3 = (fn < 3) ? fn : fn - 3;
      const short8* ib = (fn < 3) ? i0p : i1p;
      bF[0][fn] = ib[bn[f3] * 5 + slc[f3]];
    }

    int rn = 0, sn = 0, r2m = 0;   // r2m = (2*rn) % 5
    #pragma unroll 2
    for (int rs = 0; rs < 81; rs++){
      int cur = rs & 1, nxt = cur ^ 1;
      sn++;
      if (sn == 9){ sn = 0; rn++; r2m += 2; if (r2m >= 5) r2m -= 5; }
      int nrs = (rs < 80) ? rs + 1 : 80;
      int roff = rn * 20 + sn;
      const short8* apn = ap + (size_t)nrs * 2048;
      #pragma unroll
      for (int fo = 0; fo < 4; fo++) aF[nxt][fo] = apn[fo * 64];
      #pragma unroll
      for (int fn = 0; fn < 6; fn++){
        int f3 = (fn < 3) ? fn : fn - 3;
        const short8* ib = (fn < 3) ? i0p : i1p;
        int sl = slc[f3] + r2m; if (sl >= 5) sl -= 5;
        bF[nxt][fn] = ib[(bn[f3] + roff) * 5 + sl];
      }
      #pragma unroll
      for (int fo = 0; fo < 4; fo++)
        #pragma unroll
        for (int fn = 0; fn < 6; fn++)
          acc[fo][fn] = __builtin_amdgcn_mfma_f32_16x16x32_bf16(aF[cur][fo], bF[cur][fn], acc[fo][fn], 0, 0, 0);
    }
  }

  #pragma unroll
  for (int fn = 0; fn < 6; fn++){
    int im = (fn < 3) ? 0 : 1;
    int f3 = (fn < 3) ? fn : fn - 3;
    int pos = f3 * 16 + l15;
    if (pos < 36){
      float* cb = caps4 + ((size_t)kq * 256 + b0 + im) * 9216;
      #pragma unroll
      for (int fo = 0; fo < 4; fo++){
        int ob = wid * 64 + fo * 16 + quad * 4;
        #pragma unroll
        for (int rr = 0; rr < 4; rr++)
          cb[(size_t)(ob + rr) * 36 + pos] = acc[fo][fn][rr];
      }
    }
  }
}

// sum 4 kq-partials + bias, then squash over 8-element capsules -> caps
__global__ __launch_bounds__(256) void squash4_kernel(const float* __restrict__ caps4,
    const float* __restrict__ bias, float* __restrict__ caps){
  size_t cid = (size_t)blockIdx.x * 256 + threadIdx.x;   // 294912
  size_t base = cid * 8;
  const size_t STR = 2359296;   // 256*9216
  float4 a0 = *(const float4*)(caps4 + base);
  float4 a1 = *(const float4*)(caps4 + base + 4);
  #pragma unroll
  for (int k = 1; k < 4; k++){
    float4 q0 = *(const float4*)(caps4 + k * STR + base);
    float4 q1 = *(const float4*)(caps4 + k * STR + base + 4);
    a0.x+=q0.x; a0.y+=q0.y; a0.z+=q0.z; a0.w+=q0.w;
    a1.x+=q1.x; a1.y+=q1.y; a1.z+=q1.z; a1.w+=q1.w;
  }
  int off = (int)(base % 9216);
  float v[8] = {a0.x,a0.y,a0.z,a0.w,a1.x,a1.y,a1.z,a1.w};
  #pragma unroll
  for (int e = 0; e < 8; e++) v[e] += bias[(off + e) / 36];
  float msq = 0.f;
  #pragma unroll
  for (int e = 0; e < 8; e++) msq += v[e]*v[e];
  float scale = sqrtf(msq) / (1.f + msq);
  float* cp = caps + base;
  #pragma unroll
  for (int e = 0; e < 8; e++) cp[e] = v[e]*scale;
}

// u_hat[b,i,jd] = sum_k W[i,jd,k]*caps[b,i,k]  -> bf16, layout [b][i][160]
__global__ __launch_bounds__(256) void uhat_kernel(const float* __restrict__ caps,
    const float* __restrict__ Wt, __hip_bfloat16* __restrict__ uh){
  __shared__ float cl[4096];
  int i0 = blockIdx.x * 32;
  int b0 = blockIdx.y * 16;
  int t = threadIdx.x;
  for (int idx = t; idx < 4096; idx += 256){
    int b_l = idx >> 8;
    int rest = idx & 255;
    cl[idx] = caps[((size_t)(b0 + b_l) * 1152 + i0 + (rest >> 3)) * 8 + (rest & 7)];
  }
  __syncthreads();
  int wid = t >> 6, l = t & 63;
  for (int ii = 0; ii < 8; ii++){
    int i = i0 + ii * 4 + wid;
    float wreg[3][8];
    #pragma unroll
    for (int m = 0; m < 3; m++){
      int jd = m * 64 + l;
      if (jd < 160){
        const float4* wp = (const float4*)&Wt[((size_t)i * 160 + jd) * 8];
        float4 p0 = wp[0], p1 = wp[1];
        wreg[m][0]=p0.x; wreg[m][1]=p0.y; wreg[m][2]=p0.z; wreg[m][3]=p0.w;
        wreg[m][4]=p1.x; wreg[m][5]=p1.y; wreg[m][6]=p1.z; wreg[m][7]=p1.w;
      }
    }
    for (int b_l = 0; b_l < 16; b_l++){
      const float4* cp4 = (const float4*)&cl[(b_l * 32 + ii * 4 + wid) * 8];
      float4 ca = cp4[0], cb = cp4[1];
      float ck[8] = {ca.x, ca.y, ca.z, ca.w, cb.x, cb.y, cb.z, cb.w};
      size_t ubase = ((size_t)(b0 + b_l) * 1152 + i) * 160;
      #pragma unroll
      for (int m = 0; m < 3; m++){
        int jd = m * 64 + l;
        if (jd < 160){
          float uv = 0.f;
          #pragma unroll
          for (int k = 0; k < 8; k++) uv = fmaf(wreg[m][k], ck[k], uv);
          uh[ubase + jd] = __float2bfloat16(uv);
        }
      }
    }
  }
}

// fused routing iteration: (dot with v -> b update -> softmax c) + weighted
// sum + squash, one streaming pass over u_hat. mode: 0=uniform c (iter0),
// 1=first dot (b_old=0, write b), 2=dot + b_old (no write).
// bbuf layout: [b][i][10].
__global__ __launch_bounds__(640, 2) void route_kernel(
    const __hip_bfloat16* __restrict__ u, const float* __restrict__ vin,
    const float* __restrict__ dcb, float* __restrict__ bbuf,
    float* __restrict__ vout, int mode){
  __shared__ float vs[160];
  __shared__ float dotb[320];   // [i_local 32][j 10]
  __shared__ float cl[320];
  __shared__ float sp[4][160];
  int b = blockIdx.x;
  int t = threadIdx.x;
  int ipar = t / 160;
  int jd   = t - ipar * 160;
  int j    = jd >> 4;
  if (mode && t < 160) vs[t] = vin[b * 160 + t];
  __syncthreads();
  const __hip_bfloat16* ub = u + (size_t)b * 184320;
  float sacc = 0.f;
  for (int ch = 0; ch < 36; ch++){
    int ibase = ch * 32 + ipar * 8;
    float ureg[8];
    #pragma unroll
    for (int ii = 0; ii < 8; ii++)
      ureg[ii] = __bfloat162float(ub[(size_t)(ibase + ii) * 160 + jd]);
    if (mode){
      #pragma unroll
      for (int ii = 0; ii < 8; ii++){
        float pp = ureg[ii] * vs[jd];
        pp += __shfl_xor(pp, 1, 16);
        pp += __shfl_xor(pp, 2, 16);
        pp += __shfl_xor(pp, 4, 16);
        pp += __shfl_xor(pp, 8, 16);
        if ((jd & 15) == 0) dotb[(ipar * 8 + ii) * 10 + j] = pp;
      }
      __syncthreads();
      if (t < 320){
        float val = dotb[t];
        float* bg = bbuf + (size_t)b * 11520 + ch * 320 + t;
        if (mode == 2) val += *bg;
        else *bg = val;
        dotb[t] = val;
      }
      __syncthreads();
      if (t < 32){
        float dv[10]; float mx = -1e30f;
        #pragma unroll
        for (int q = 0; q < 10; q++){ dv[q] = dotb[t * 10 + q]; mx = fmaxf(mx, dv[q]); }
        float se = 0.f;
        #pragma unroll
        for (int q = 0; q < 10; q++){ dv[q] = __expf(dv[q] - mx); se += dv[q]; }
        float inv = 1.f / se;
        #pragma unroll
        for (int q = 0; q < 10; q++) cl[t * 10 + q] = dv[q] * inv;
      }
      __syncthreads();
      #pragma unroll
      for (int ii = 0; ii < 8; ii++)
        sacc = fmaf(cl[(ipar * 8 + ii) * 10 + j], ureg[ii], sacc);
    } else {
      #pragma unroll
      for (int ii = 0; ii < 8; ii++) sacc += ureg[ii];
    }
  }
  if (!mode) sacc *= 0.1f;
  sp[ipar][jd] = sacc;
  __syncthreads();
  if (t < 160){
    float sv = sp[0][t] + sp[1][t] + sp[2][t] + sp[3][t] + dcb[t];
    float msq = sv * sv;
    msq += __shfl_xor(msq, 1, 16);
    msq += __shfl_xor(msq, 2, 16);
    msq += __shfl_xor(msq, 4, 16);
    msq += __shfl_xor(msq, 8, 16);
    float scale = sqrtf(msq) / (1.f + msq);
    vout[b * 160 + t] = sv * scale;
  }
}

extern "C" void kernel_launch(void* const* d_in, const int* in_sizes, int n_in,
                              void* d_out, int out_size, void* d_ws, size_t ws_size,
                              hipStream_t stream){
  (void)in_sizes; (void)n_in; (void)out_size; (void)ws_size;
  const float* x   = (const float*)d_in[0];
  const float* w1  = (const float*)d_in[1];
  const float* b1  = (const float*)d_in[2];
  const float* w2  = (const float*)d_in[3];
  const float* b2  = (const float*)d_in[4];
  const float* W   = (const float*)d_in[5];
  const float* dcb = (const float*)d_in[6];
  float* out = (float*)d_out;

  char* ws = (char*)d_ws;
  __hip_bfloat16* ht  = (__hip_bfloat16*)(ws);
  ushort* A2s  = (ushort*)(ws + 52428800);
  float* caps4 = (float*)(ws + 63045632);
  __hip_bfloat16* uh = (__hip_bfloat16*)(ws);        // overlays ht/A2/caps4 (dead)
  float* caps = (float*)(ws + 100794368);
  float* bbuf = (float*)(ws + 110231552);
  float* vbuf = (float*)(ws + 122028032);

  conv1_kernel<<<dim3(256, 8), 640, 0, stream>>>(x, w1, b1, ht);
  arepack_kernel<<<256, 256, 0, stream>>>(w2, A2s);
  conv2_mfma_kernel<<<512, 256, 0, stream>>>(ht, (const short8*)A2s, caps4);
  squash4_kernel<<<1152, 256, 0, stream>>>(caps4, b2, caps);
  uhat_kernel<<<dim3(36, 16), 256, 0, stream>>>(caps, W, uh);
  route_kernel<<<256, 640, 0, stream>>>(uh, vbuf, dcb, bbuf, vbuf, 0);
  route_kernel<<<256, 640, 0, stream>>>(uh, vbuf, dcb, bbuf, vbuf, 1);
  route_kernel<<<256, 640, 0, stream>>>(uh, vbuf, dcb, bbuf, out, 2);
}